// Round 1
// 5779.846 us; speedup vs baseline: 1.0500x; 1.0500x over previous
//
#include <hip/hip_runtime.h>
#include <stdint.h>
#include <stdio.h>

// ---------------------------------------------------------------------------
// DilatedSparseRnnStack, round 5: L2-footprint shrink.
// Round-4 structure (persistent XCD-local clusters, weights LDS-resident,
// L2-atomic barrier + buffer_inv sc0) kept. Changes:
//  - Layer 0 (dil=1): dH==prevH and weightedC==prevC algebraically, so the
//    dH weight block is FOLDED into the prevH block (fp32 sum -> bf16) and
//    the C0 ring is deleted. K0: 320 -> 192.
//  - C3 ring (dil=12, largest/longest-lived) moved to LDS ([slot][j][row]
//    layout, bank-conflict-free scalar access). WG-private, no sync needed.
//  - Per-cluster global ring footprint drops 3.87 MB -> ~2.1 MB so the
//    h-rings/outb/C1/C2 stay resident in the XCD's 4 MB L2 (round-4 counters
//    showed 766 MB HBM WRITE = C-ring writeback thrash).
//  - x[t+1] slice prefetched into L2 during the layer-2 phase.
// ---------------------------------------------------------------------------

typedef __attribute__((ext_vector_type(8))) short short8;
typedef __attribute__((ext_vector_type(4))) float f32x4;

#define DEVINL static __device__ __forceinline__

constexpr int TT = 256, BBATCH = 1024, INW = 64, HSW = 128, OSW = 128, NO = 8;
constexpr int ROWS = 128;                 // batch rows per cluster

constexpr int KLa[4]   = {192, 384, 448, 384};   // layer-0 folded: 320 -> 192
constexpr int DILa[4]  = {1, 3, 6, 12};
constexpr int PERa[4]  = {2, 4, 7, 13};   // h ring period = dil+1
constexpr int LDWa[4]  = {200, 392, 456, 392};            // padded LDS strides
constexpr int WOFFa[4] = {0, 6400, 18944, 33536};         // ushort offsets

constexpr int GSTRIDE = 34;                        // 32 cols + 2 pad (2-way free)
constexpr int GATES_B = 46080 * 2;                 // 92,160 weight bytes
constexpr int BIAS_B  = GATES_B + 128 * GSTRIDE * 4;   // 109,568
constexpr int WOUT_B  = BIAS_B + 128 * 4;              // 110,080
constexpr int WSTR    = 129;                           // wout pad
constexpr int BOUT_B  = WOUT_B + 8 * WSTR * 4;         // 114,208
constexpr int C3_B    = BOUT_B + 32;                   // 114,240
constexpr int LDS_BYTES = C3_B + 12 * 8 * 128 * 4;     // 163,392 (<= 160 KiB)

// workspace layout (bytes)
//   [0,2048)    per-cluster barrier counters (c*256)
//   [2048,2560) per-XCD rank counters (c*64)
constexpr size_t WSBASE    = 4096;
constexpr size_t BH_OFF[4] = {0, 65536, 196608, 425984}; // h rings (P_l slots of 128x128 bf16)
constexpr size_t OUTB_OFF  = 851968;                     // 4 x 128x128 bf16
constexpr size_t CB_OFF    = 983040;                     // C rings: layers 1,2 only
constexpr size_t C1_SZ     = 393216;                     // 3 slots x 128x256 f32
constexpr size_t C2_SZ     = 786432;                     // 6 slots x 128x256 f32
constexpr size_t CLSZ      = CB_OFF + C1_SZ + C2_SZ;     // 2,162,688 (~2.1 MB)
constexpr size_t WS_NEED   = WSBASE + 8 * CLSZ;          // ~17.3 MB

__host__ __device__ constexpr int seg_type(int L, int k) {
  // 0 = x (fp32), 1 = prev-layer out, 2 = prevH, 3 = dH
  if (L == 0) return k < 64 ? 0 : 2;                    // dH folded into prevH
  if (L == 1) return k < 128 ? 1 : (k < 256 ? 2 : 3);
  if (L == 2) return k < 128 ? 1 : (k < 192 ? 0 : (k < 320 ? 2 : 3));
  return k < 128 ? 1 : (k < 256 ? 2 : 3);
}
__host__ __device__ constexpr int seg_start(int L, int k) {
  if (L == 0) return k < 64 ? 0 : 64;
  if (L == 1) return k < 128 ? 0 : (k < 256 ? 128 : 256);
  if (L == 2) return k < 128 ? 0 : (k < 192 ? 128 : (k < 320 ? 192 : 320));
  return k < 128 ? 0 : (k < 256 ? 128 : 256);
}

template <int N> struct IC { static constexpr int value = N; };

DEVINL unsigned short f2bf(float f) {        // RNE fp32 -> bf16
  union { float f; uint32_t u; } v; v.f = f;
  return (unsigned short)((v.u + 0x7FFFu + ((v.u >> 16) & 1u)) >> 16);
}
DEVINL float bf2f(unsigned short h) {
  union { uint32_t u; float f; } v; v.u = ((uint32_t)h) << 16;
  return v.f;
}
DEVINL float sigm(float x)  { return 1.0f / (1.0f + __expf(-x)); }
DEVINL float tanh_(float x) { return 1.0f - 2.0f / (__expf(2.0f * x) + 1.0f); }

DEVINL short8 zero_s8() { short8 v; for (int i = 0; i < 8; i++) v[i] = 0; return v; }
DEVINL f32x4  zero_f4() { f32x4  v; for (int i = 0; i < 4; i++) v[i] = 0.f; return v; }

DEVINL f32x4 mfma16(short8 a, short8 b, f32x4 c) {
  return __builtin_amdgcn_mfma_f32_16x16x32_bf16(a, b, c, 0, 0, 0);
}

DEVINL short8 ld8f(const float* p) {         // 8 fp32 -> bf16x8 fragment
  const f32x4 u0 = *(const f32x4*)p;
  const f32x4 u1 = *(const f32x4*)(p + 4);
  short8 r;
  r[0] = (short)f2bf(u0[0]); r[1] = (short)f2bf(u0[1]);
  r[2] = (short)f2bf(u0[2]); r[3] = (short)f2bf(u0[3]);
  r[4] = (short)f2bf(u1[0]); r[5] = (short)f2bf(u1[1]);
  r[6] = (short)f2bf(u1[2]); r[7] = (short)f2bf(u1[3]);
  return r;
}

// XCD-local cluster barrier: stores drained to L2 by __syncthreads' vmcnt(0)
// (L1 write-through); acquire = invalidate this CU's vector L1 only.
DEVINL void cluster_barrier(unsigned* ctr, unsigned target) {
  __syncthreads();
  if (threadIdx.x == 0) {
    __hip_atomic_fetch_add(ctr, 1u, __ATOMIC_RELAXED, __HIP_MEMORY_SCOPE_AGENT);
    while (__hip_atomic_load(ctr, __ATOMIC_RELAXED, __HIP_MEMORY_SCOPE_AGENT) < target)
      __builtin_amdgcn_s_sleep(1);
  }
  __syncthreads();
  asm volatile("buffer_inv sc0" ::: "memory");
}

__global__ void __launch_bounds__(256, 1)
rnn_stack_kernel(const float* __restrict__ x,
                 const float* __restrict__ W0, const float* __restrict__ b0,
                 const float* __restrict__ W1, const float* __restrict__ b1,
                 const float* __restrict__ W2, const float* __restrict__ b2,
                 const float* __restrict__ W3, const float* __restrict__ b3,
                 const float* __restrict__ Wout, const float* __restrict__ bout,
                 float* __restrict__ yout, char* __restrict__ ws)
{
  extern __shared__ char smem[];
  unsigned short* wlds = (unsigned short*)smem;
  float* gates = (float*)(smem + GATES_B);
  float* biasl = (float*)(smem + BIAS_B);
  float* woutl = (float*)(smem + WOUT_B);
  float* boutl = (float*)(smem + BOUT_B);
  float* c3l   = (float*)(smem + C3_B);     // [12 slots][8 j][128 rows] f32

  const int tid = threadIdx.x;

  // ---- runtime cluster formation: c = physical XCD, g = rank on that XCD ----
  __shared__ unsigned s_cg;
  if (tid == 0) {
    unsigned xcc;
    asm volatile("s_getreg_b32 %0, hwreg(HW_REG_XCC_ID)" : "=s"(xcc));
    xcc &= 7u;
    unsigned rank = __hip_atomic_fetch_add(
        (unsigned*)(ws + 2048 + (size_t)xcc * 64), 1u,
        __ATOMIC_RELAXED, __HIP_MEMORY_SCOPE_AGENT);
    s_cg = (xcc << 8) | (rank & 31u);
  }
  __syncthreads();
  const int c = s_cg >> 8;         // cluster == XCD, owns batch rows c*128..+127
  const int g = s_cg & 255;        // column-group 0..31 (owns SS cols g*8..g*8+7)

  unsigned* ctr = (unsigned*)(ws + (size_t)c * 256);
  char* cb = ws + WSBASE + (size_t)c * CLSZ;
  unsigned short* bufH[4];
  unsigned short* outb[4];
#pragma unroll
  for (int l = 0; l < 4; l++) {
    bufH[l] = (unsigned short*)(cb + BH_OFF[l]);
    outb[l] = (unsigned short*)(cb + OUTB_OFF + (size_t)l * ROWS * OSW * 2);
  }
  float* bufC1 = (float*)(cb + CB_OFF + (size_t)g * (3 * ROWS * 8 * 4));
  float* bufC2 = (float*)(cb + CB_OFF + C1_SZ + (size_t)g * (6 * ROWS * 8 * 4));

  // ---- startup: weight/bias slices -> LDS (bf16); layer-0 dH block folded ----
  {
    const float* Wsrc[4] = {W0, W1, W2, W3};
    const float* bsrc[4] = {b0, b1, b2, b3};
    for (int l = 0; l < 4; l++) {
      const int K = KLa[l], LDW = LDWa[l];
      const int Ksrc = (l == 0) ? 320 : K;             // W0 rows are length 320
      for (int n = 0; n < 32; n++) {
        const int grow = (n >> 3) * 256 + g * 8 + (n & 7);   // gate*SS + jglob
        const float* src = Wsrc[l] + (size_t)grow * Ksrc;
        unsigned short* dst = wlds + WOFFa[l] + n * LDW;
        for (int k = tid; k < K; k += 256) {
          float v = src[k];
          if (l == 0 && k >= 64) v += src[k + 128];    // fold W_dH into W_prevH
          dst[k] = f2bf(v);
        }
      }
      if (tid < 32) biasl[l * 32 + tid] = bsrc[l][(tid >> 3) * 256 + g * 8 + (tid & 7)];
    }
    for (int i = tid; i < 8 * 128; i += 256) woutl[(i >> 7) * WSTR + (i & 127)] = Wout[i];
    if (tid < 8) boutl[tid] = bout[tid];
  }
  __syncthreads();

  f32x4 pc[4];                     // prevC (fp32, thread-private: 4 (row,j) per layer)
#pragma unroll
  for (int l = 0; l < 4; l++) pc[l] = zero_f4();
  unsigned phase = 0;

  const int wv = tid >> 6, lane = tid & 63, lm = lane & 15, quad = lane >> 4;
  const int m0 = wv * 32;          // wave's first batch row (2 M-tiles per wave)

  for (int t = 0; t < TT; t++) {
    auto do_layer = [&](auto Lc) {
      constexpr int L = decltype(Lc)::value;
      constexpr int K   = KLa[L];
      constexpr int NKT = K / 32;
      constexpr int DL  = DILa[L];
      constexpr int P   = PERa[L];
      constexpr int LDW = LDWa[L];
      const unsigned short* wl = wlds + WOFFa[L];
      const unsigned short* phb =
          (t >= 1) ? bufH[L] + (size_t)((t - 1) % P) * ROWS * HSW : nullptr;
      const unsigned short* dhb =
          (t >= DL) ? bufH[L] + (size_t)((t - DL) % P) * ROWS * HSW : phb;
      const unsigned short* ob = (L > 0) ? outb[L - 1] : nullptr;
      const float* xb = x + ((size_t)t * BBATCH + (size_t)c * ROWS) * INW;

      // ---- gates[128 x 32] = xh @ Wslice^T  (MFMA 16x16x32 bf16) ----
      f32x4 acc00 = zero_f4(), acc01 = zero_f4(), acc10 = zero_f4(), acc11 = zero_f4();
#pragma unroll
      for (int kt = 0; kt < NKT; kt++) {
        const int sty  = seg_type(L, kt * 32);    // folds at compile time
        const int sst  = seg_start(L, kt * 32);
        const int kloc = kt * 32 - sst + quad * 8;
        short8 a0, a1;
        if (sty == 0) {
          const float* p = xb + (size_t)(m0 + lm) * INW + kloc;
          a0 = ld8f(p);
          a1 = ld8f(p + 16 * INW);
        } else {
          const unsigned short* sb = (sty == 1) ? ob : ((sty == 2) ? phb : dhb);
          if (sb) {
            const unsigned short* p = sb + (size_t)(m0 + lm) * HSW + kloc;
            a0 = *(const short8*)p;
            a1 = *(const short8*)(p + 16 * HSW);
          } else {
            a0 = zero_s8();
            a1 = zero_s8();
          }
        }
        const short8 bf0 = *(const short8*)(wl + (size_t)lm * LDW + kt * 32 + quad * 8);
        const short8 bf1 = *(const short8*)(wl + (size_t)(16 + lm) * LDW + kt * 32 + quad * 8);
        acc00 = mfma16(a0, bf0, acc00);
        acc01 = mfma16(a0, bf1, acc01);
        acc10 = mfma16(a1, bf0, acc10);
        acc11 = mfma16(a1, bf1, acc11);
      }
      // C-layout: col = lane&15, row = quad*4 + reg  (m89-verified)
#pragma unroll
      for (int r = 0; r < 4; r++) {
        gates[(m0 + quad * 4 + r) * GSTRIDE + lm]           = acc00[r];
        gates[(m0 + quad * 4 + r) * GSTRIDE + 16 + lm]      = acc01[r];
        gates[(m0 + 16 + quad * 4 + r) * GSTRIDE + lm]      = acc10[r];
        gates[(m0 + 16 + quad * 4 + r) * GSTRIDE + 16 + lm] = acc11[r];
      }
      __syncthreads();

      // ---- cell elementwise: thread owns (row = tid&127, j0 = (tid>>7)*4 .. +3) ----
      {
        const int row = tid & 127, j0 = (tid >> 7) * 4;
        const f32x4 G0 = *(const f32x4*)&gates[row * GSTRIDE + 0 + j0];
        const f32x4 G1 = *(const f32x4*)&gates[row * GSTRIDE + 8 + j0];
        const f32x4 G2 = *(const f32x4*)&gates[row * GSTRIDE + 16 + j0];
        const f32x4 G3 = *(const f32x4*)&gates[row * GSTRIDE + 24 + j0];
        float* cs = nullptr;
        if constexpr (L == 1) cs = bufC1 + ((size_t)(t % 3) * ROWS + row) * 8 + j0;
        if constexpr (L == 2) cs = bufC2 + ((size_t)(t % 6) * ROWS + row) * 8 + j0;
        f32x4 dC = zero_f4();
        if constexpr (L == 1 || L == 2) {
          if (t >= DL) dC = *(const f32x4*)cs;     // C from t-dil (WG-private, L2)
        }
        if constexpr (L == 3) {
          if (t >= DL) {
            const int sl = t % 12;
#pragma unroll
            for (int q = 0; q < 4; q++) dC[q] = c3l[(sl * 8 + j0 + q) * 128 + row];
          }
        }
        const f32x4 pcv = pc[L];
        f32x4 nC, wh;
#pragma unroll
        for (int q = 0; q < 4; q++) {
          const float fg = sigm(G0[q] + biasl[L * 32 + 0  + j0 + q] + 1.0f);
          const float cd = tanh_(G1[q] + biasl[L * 32 + 8  + j0 + q]);
          const float og = sigm(G3[q] + biasl[L * 32 + 24 + j0 + q]);
          float wc;
          if constexpr (L == 0) {
            wc = pcv[q];                  // dil=1: alpha*prevC+(1-alpha)*prevC
          } else {
            const float al = sigm(G2[q] + biasl[L * 32 + 16 + j0 + q]);
            wc = (t >= DL) ? (al * pcv[q] + (1.0f - al) * dC[q]) : pcv[q];
          }
          const float nc = (t >= 1) ? (fg * wc + (1.0f - fg) * cd) : cd;
          nC[q] = nc;
          wh[q] = og * nc;
        }
        if constexpr (L == 1 || L == 2) *(f32x4*)cs = nC;
        if constexpr (L == 3) {
          const int sl = t % 12;
#pragma unroll
          for (int q = 0; q < 4; q++) c3l[(sl * 8 + j0 + q) * 128 + row] = nC[q];
        }
        pc[L] = nC;
        ushort4 wb;
        wb.x = f2bf(wh[0]); wb.y = f2bf(wh[1]); wb.z = f2bf(wh[2]); wb.w = f2bf(wh[3]);
        const int jg = g * 8 + j0;
        if (g < 16) {               // whole[:, :128] -> next-layer input
          *(ushort4*)(outb[L] + (size_t)row * OSW + jg) = wb;
        } else {                    // whole[:, 128:] -> h ring slot t%(dil+1)
          *(ushort4*)(bufH[L] + ((size_t)(t % P) * ROWS + row) * HSW + (jg - 128)) = wb;
        }
      }
      phase++;
      cluster_barrier(ctr, 32u * phase);
    };
    do_layer(IC<0>{});
    do_layer(IC<1>{});

    // prefetch x[t+1] slice into L2 (keep-alive so it isn't DCE'd); its HBM
    // latency hides under the layer-2/3 phases instead of stalling L0 of t+1.
    if (t + 1 < TT) {
      const float* xn = x + ((size_t)(t + 1) * BBATCH + (size_t)c * ROWS) * INW;
      float acc = 0.f;
#pragma unroll
      for (int i = 0; i < 8; i++) {
        const f32x4 v = *(const f32x4*)(xn + (size_t)tid * 32 + i * 4);
        acc += v[0];
      }
      asm volatile("" :: "v"(acc));
    }

    do_layer(IC<2>{});
    do_layer(IC<3>{});

    // ---- y = out3 @ Wout^T + bout; wave w -> row g*4+w, 8 lanes per (r,o) ----
    {
      const int o = (tid >> 3) & 7;
      const int s = tid & 7;
      const int r = g * 4 + (tid >> 6);
      const unsigned short* orow = outb[3] + (size_t)r * OSW;
      float part = 0.f;
#pragma unroll
      for (int i = 0; i < 16; i++) {
        const int k = s * 16 + i;
        part += bf2f(orow[k]) * woutl[o * WSTR + k];
      }
      part += __shfl_down(part, 4);
      part += __shfl_down(part, 2);
      part += __shfl_down(part, 1);
      if (s == 0)
        yout[((size_t)t * BBATCH + (size_t)c * ROWS + r) * NO + o] = part + boutl[o];
    }
  }
}

extern "C" void kernel_launch(void* const* d_in, const int* in_sizes, int n_in,
                              void* d_out, int out_size, void* d_ws, size_t ws_size,
                              hipStream_t stream) {
  const float* x    = (const float*)d_in[0];
  const float* W0   = (const float*)d_in[1];
  const float* b0   = (const float*)d_in[2];
  const float* W1   = (const float*)d_in[3];
  const float* b1   = (const float*)d_in[4];
  const float* W2   = (const float*)d_in[5];
  const float* b2   = (const float*)d_in[6];
  const float* W3   = (const float*)d_in[7];
  const float* b3   = (const float*)d_in[8];
  const float* Wout = (const float*)d_in[9];
  const float* bout = (const float*)d_in[10];
  float* out = (float*)d_out;
  char* ws = (char*)d_ws;

  if (ws_size < WS_NEED) {
    fprintf(stderr, "kernel_launch: ws_size %zu < needed %zu\n", ws_size, (size_t)WS_NEED);
    return;
  }

  // zero barrier + rank counters (ws is poisoned 0xAA before every launch)
  hipMemsetAsync(d_ws, 0, 4096, stream);

  hipError_t e = hipFuncSetAttribute((const void*)rnn_stack_kernel,
                                     hipFuncAttributeMaxDynamicSharedMemorySize,
                                     LDS_BYTES);
  if (e != hipSuccess) fprintf(stderr, "hipFuncSetAttribute: %d\n", (int)e);

  rnn_stack_kernel<<<dim3(256), dim3(256), LDS_BYTES, stream>>>(
      x, W0, b0, W1, b1, W2, b2, W3, b3, Wout, bout, out, ws);
  e = hipGetLastError();
  if (e != hipSuccess) fprintf(stderr, "launch error: %d\n", (int)e);
}

// Round 2
// 4493.076 us; speedup vs baseline: 1.3507x; 1.2864x over previous
//
#include <hip/hip_runtime.h>
#include <stdint.h>
#include <stdio.h>

// ---------------------------------------------------------------------------
// DilatedSparseRnnStack, round 6: latency-chain decoupling.
// Round-5 data placement kept (weights LDS, C3 ring LDS, C1/C2+h rings in an
// L2-resident ~2.1MB/cluster workspace). Structural changes:
//  - IN-REGISTER CELL: gate exchange via __shfl_xor(8); gates LDS buffer and
//    both per-phase __syncthreads deleted. Bias folded into acc init.
//  - PER-WAVE BARRIERS: wave w of every WG owns rows w*32..+31 exclusively
//    (MFMA, cell, publish, epilogue all row-local) -> 4 independent barrier
//    groups per cluster; waves fully decoupled, no WG-wide sync in main loop.
//  - DISTRIBUTED FLAGS: per-WG epoch words; arrive = vmcnt(0)+store; wait =
//    lane-parallel atomic loads + __all. No serialized 32-way atomic RMW.
//  - PRE/POST PIPELINE: non-ob MFMA segments (x/prevH/dH) + epilogue execute
//    between arrive(p) and wait(p), hiding barrier detection + load latency.
// ---------------------------------------------------------------------------

typedef __attribute__((ext_vector_type(8))) short short8;
typedef __attribute__((ext_vector_type(4))) float f32x4;

#define DEVINL static __device__ __forceinline__

constexpr int TT = 256, BBATCH = 1024, INW = 64, HSW = 128, OSW = 128, NO = 8;
constexpr int ROWS = 128;                 // batch rows per cluster

constexpr int KLa[4]   = {192, 384, 448, 384};   // layer-0 dH folded: 320 -> 192
constexpr int DILa[4]  = {1, 3, 6, 12};
constexpr int PERa[4]  = {2, 4, 7, 13};   // h ring period = dil+1
constexpr int LDWa[4]  = {200, 392, 456, 392};            // padded LDS strides
constexpr int WOFFa[4] = {0, 6400, 18944, 33536};         // ushort offsets

constexpr int BIAS_B  = 46080 * 2;                 // 92,160 weight bytes
constexpr int WOUT_B  = BIAS_B + 128 * 4;          // 92,672
constexpr int WSTR    = 129;                       // wout pad
constexpr int BOUT_B  = WOUT_B + 8 * WSTR * 4;     // 96,800
constexpr int C3_B    = BOUT_B + 32;               // 96,832
constexpr int C3STR   = 132;                       // c3 row-stride pad (bank-clean)
constexpr int LDS_BYTES = C3_B + 96 * C3STR * 4;   // 147,520 (<= 160 KiB)

// workspace layout (bytes)
//   [0,4096)     barrier flags: cluster c, wave w -> ws + c*512 + w*128, 32 words
//   [4096,4608)  per-XCD rank counters (c*64)
constexpr size_t WSBASE    = 8192;
constexpr size_t BH_OFF[4] = {0, 65536, 196608, 425984}; // h rings (P_l slots of 128x128 bf16)
constexpr size_t OUTB_OFF  = 851968;                     // 4 x 128x128 bf16
constexpr size_t CB_OFF    = 983040;                     // C rings: layers 1,2 only
constexpr size_t C1_SZ     = 393216;                     // 32 wg x 3 slots x 8 j x 128 rows f32
constexpr size_t C2_SZ     = 786432;                     // 32 wg x 6 slots x 8 j x 128 rows f32
constexpr size_t CLSZ      = CB_OFF + C1_SZ + C2_SZ;     // 2,162,688 (~2.1 MB)
constexpr size_t WS_NEED   = WSBASE + 8 * CLSZ;          // ~17.3 MB

__host__ __device__ constexpr int seg_type(int L, int k) {
  // 0 = x (fp32), 1 = prev-layer out, 2 = prevH, 3 = dH
  if (L == 0) return k < 64 ? 0 : 2;                    // dH folded into prevH
  if (L == 1) return k < 128 ? 1 : (k < 256 ? 2 : 3);
  if (L == 2) return k < 128 ? 1 : (k < 192 ? 0 : (k < 320 ? 2 : 3));
  return k < 128 ? 1 : (k < 256 ? 2 : 3);
}
__host__ __device__ constexpr int seg_start(int L, int k) {
  if (L == 0) return k < 64 ? 0 : 64;
  if (L == 1) return k < 128 ? 0 : (k < 256 ? 128 : 256);
  if (L == 2) return k < 128 ? 0 : (k < 192 ? 128 : (k < 320 ? 192 : 320));
  return k < 128 ? 0 : (k < 256 ? 128 : 256);
}

template <int N> struct IC { static constexpr int value = N; };

DEVINL unsigned short f2bf(float f) {        // RNE fp32 -> bf16
  union { float f; uint32_t u; } v; v.f = f;
  return (unsigned short)((v.u + 0x7FFFu + ((v.u >> 16) & 1u)) >> 16);
}
DEVINL float bf2f(unsigned short h) {
  union { uint32_t u; float f; } v; v.u = ((uint32_t)h) << 16;
  return v.f;
}
DEVINL float sigm(float x)  { return 1.0f / (1.0f + __expf(-x)); }
DEVINL float tanh_(float x) { return 1.0f - 2.0f / (__expf(2.0f * x) + 1.0f); }

DEVINL short8 zero_s8() { short8 v; for (int i = 0; i < 8; i++) v[i] = 0; return v; }
DEVINL f32x4  zero_f4() { f32x4  v; for (int i = 0; i < 4; i++) v[i] = 0.f; return v; }

DEVINL f32x4 mfma16(short8 a, short8 b, f32x4 c) {
  return __builtin_amdgcn_mfma_f32_16x16x32_bf16(a, b, c, 0, 0, 0);
}

DEVINL short8 ld8f(const float* p) {         // 8 fp32 -> bf16x8 fragment
  const f32x4 u0 = *(const f32x4*)p;
  const f32x4 u1 = *(const f32x4*)(p + 4);
  short8 r;
  r[0] = (short)f2bf(u0[0]); r[1] = (short)f2bf(u0[1]);
  r[2] = (short)f2bf(u0[2]); r[3] = (short)f2bf(u0[3]);
  r[4] = (short)f2bf(u1[0]); r[5] = (short)f2bf(u1[1]);
  r[6] = (short)f2bf(u1[2]); r[7] = (short)f2bf(u1[3]);
  return r;
}

__global__ void __launch_bounds__(256, 1)
rnn_stack_kernel(const float* __restrict__ x,
                 const float* __restrict__ W0, const float* __restrict__ b0,
                 const float* __restrict__ W1, const float* __restrict__ b1,
                 const float* __restrict__ W2, const float* __restrict__ b2,
                 const float* __restrict__ W3, const float* __restrict__ b3,
                 const float* __restrict__ Wout, const float* __restrict__ bout,
                 float* __restrict__ yout, char* __restrict__ ws)
{
  extern __shared__ char smem[];
  unsigned short* wlds = (unsigned short*)smem;
  float* biasl = (float*)(smem + BIAS_B);
  float* woutl = (float*)(smem + WOUT_B);
  float* boutl = (float*)(smem + BOUT_B);
  float* c3l   = (float*)(smem + C3_B);     // [(slot*8+j)*C3STR + row] f32

  const int tid = threadIdx.x;

  // ---- runtime cluster formation: c = physical XCD, g = rank on that XCD ----
  __shared__ unsigned s_cg;
  if (tid == 0) {
    unsigned xcc;
    asm volatile("s_getreg_b32 %0, hwreg(HW_REG_XCC_ID)" : "=s"(xcc));
    xcc &= 7u;
    unsigned rank = __hip_atomic_fetch_add(
        (unsigned*)(ws + 4096 + (size_t)xcc * 64), 1u,
        __ATOMIC_RELAXED, __HIP_MEMORY_SCOPE_AGENT);
    s_cg = (xcc << 8) | (rank & 31u);
  }
  __syncthreads();
  const int c = __builtin_amdgcn_readfirstlane((int)(s_cg >> 8));
  const int g = __builtin_amdgcn_readfirstlane((int)(s_cg & 255));

  char* cb = ws + WSBASE + (size_t)c * CLSZ;
  unsigned short* bufH[4];
  unsigned short* outb[4];
#pragma unroll
  for (int l = 0; l < 4; l++) {
    bufH[l] = (unsigned short*)(cb + BH_OFF[l]);
    outb[l] = (unsigned short*)(cb + OUTB_OFF + (size_t)l * ROWS * OSW * 2);
  }
  float* bufC1 = (float*)(cb + CB_OFF + (size_t)g * (3 * 8 * ROWS * 4));
  float* bufC2 = (float*)(cb + CB_OFF + C1_SZ + (size_t)g * (6 * 8 * ROWS * 4));

  // ---- startup: weight/bias slices -> LDS (bf16); layer-0 dH block folded ----
  {
    const float* Wsrc[4] = {W0, W1, W2, W3};
    const float* bsrc[4] = {b0, b1, b2, b3};
    for (int l = 0; l < 4; l++) {
      const int K = KLa[l], LDW = LDWa[l];
      const int Ksrc = (l == 0) ? 320 : K;             // W0 rows are length 320
      for (int n = 0; n < 32; n++) {
        const int grow = (n >> 3) * 256 + g * 8 + (n & 7);   // gate*SS + jglob
        const float* src = Wsrc[l] + (size_t)grow * Ksrc;
        unsigned short* dst = wlds + WOFFa[l] + n * LDW;
        for (int k = tid; k < K; k += 256) {
          float v = src[k];
          if (l == 0 && k >= 64) v += src[k + 128];    // fold W_dH into W_prevH
          dst[k] = f2bf(v);
        }
      }
      if (tid < 32) biasl[l * 32 + tid] = bsrc[l][(tid >> 3) * 256 + g * 8 + (tid & 7)];
    }
    for (int i = tid; i < 8 * 128; i += 256) woutl[(i >> 7) * WSTR + (i & 127)] = Wout[i];
    if (tid < 8) boutl[tid] = bout[tid];
  }
  __syncthreads();           // the ONLY wg-wide sync; waves decouple after this

  const int wv = tid >> 6, lane = tid & 63, lm = lane & 15, quad = lane >> 4;
  const int m0 = wv * 32;          // wave's private 32 batch rows
  const bool hi = lm >= 8;
  const int j = lm & 7;            // this lane's j-column (0..7)
  const int mrow = m0 + (hi ? 16 : 0) + quad * 4;   // first of this lane's 4 rows

  // per-wave barrier flag block: 32 words (one per WG) for (cluster c, wave wv)
  unsigned* flg = (unsigned*)(ws + (size_t)c * 512 + (size_t)wv * 128);

  f32x4 pc[4];                     // prevC (4 rows x this lane's j), per layer
#pragma unroll
  for (int l = 0; l < 4; l++) pc[l] = zero_f4();

  f32x4 acc00, acc01, acc10, acc11;    // current-phase gate accumulators

  // ---- barrier primitives (per wave-group) ----
  auto arrive = [&](unsigned ep) {
    asm volatile("s_waitcnt vmcnt(0)" ::: "memory");   // publish stores in L2
    if (lane == 0)
      __hip_atomic_store(flg + g, ep, __ATOMIC_RELAXED, __HIP_MEMORY_SCOPE_AGENT);
  };
  auto waitbar = [&](unsigned ep) {
    asm volatile("" ::: "memory");   // keep PRE loads above the poll loop
    for (;;) {
      unsigned v = __hip_atomic_load(flg + (lane & 31), __ATOMIC_RELAXED,
                                     __HIP_MEMORY_SCOPE_AGENT);
      if (__all((int)(v >= ep))) break;
      __builtin_amdgcn_s_sleep(1);
    }
    asm volatile("buffer_inv sc0" ::: "memory");   // L1 invalidate (XCD acquire)
  };

  // ---- PRE: init acc from bias, accumulate barrier-independent segments ----
  auto pre = [&](auto Lc, int t) {
    constexpr int L = decltype(Lc)::value;
    constexpr int K = KLa[L];
    constexpr int NKT = K / 32;
    constexpr int DL = DILa[L];
    constexpr int P = PERa[L];
    constexpr int LDW = LDWa[L];
    const unsigned short* wl = wlds + WOFFa[L];
    const float bb0 = biasl[L * 32 + lm] + (lm < 8 ? 1.0f : 0.0f);  // fg bias +1
    const float bb1 = biasl[L * 32 + 16 + lm];
    acc00 = (f32x4){bb0, bb0, bb0, bb0};
    acc10 = acc00;
    acc01 = (f32x4){bb1, bb1, bb1, bb1};
    acc11 = acc01;
    const unsigned short* phb =
        (t >= 1) ? bufH[L] + (size_t)((t - 1) % P) * ROWS * HSW : nullptr;
    const unsigned short* dhb =
        (t >= DL) ? bufH[L] + (size_t)((t - DL) % P) * ROWS * HSW : phb;
    const float* xb = x + ((size_t)t * BBATCH + (size_t)c * ROWS) * INW;
#pragma unroll
    for (int kt = 0; kt < NKT; kt++) {
      const int sty = seg_type(L, kt * 32);
      if (sty == 1) continue;                    // ob segments belong to POST
      const int sst = seg_start(L, kt * 32);
      const int kloc = kt * 32 - sst + quad * 8;
      short8 a0, a1;
      if (sty == 0) {
        const float* p = xb + (size_t)(m0 + lm) * INW + kloc;
        a0 = ld8f(p);
        a1 = ld8f(p + 16 * INW);
      } else {
        const unsigned short* sb = (sty == 2) ? phb : dhb;
        if (sb) {
          const unsigned short* p = sb + (size_t)(m0 + lm) * HSW + kloc;
          a0 = *(const short8*)p;
          a1 = *(const short8*)(p + 16 * HSW);
        } else {
          a0 = zero_s8();
          a1 = zero_s8();
        }
      }
      const short8 bf0 = *(const short8*)(wl + (size_t)lm * LDW + kt * 32 + quad * 8);
      const short8 bf1 = *(const short8*)(wl + (size_t)(16 + lm) * LDW + kt * 32 + quad * 8);
      acc00 = mfma16(a0, bf0, acc00);
      acc01 = mfma16(a0, bf1, acc01);
      acc10 = mfma16(a1, bf0, acc10);
      acc11 = mfma16(a1, bf1, acc11);
    }
  };

  // ---- POST: ob-segment MFMAs, in-register cell, publish ----
  auto post = [&](auto Lc, int t) {
    constexpr int L = decltype(Lc)::value;
    constexpr int K = KLa[L];
    constexpr int NKT = K / 32;
    constexpr int DL = DILa[L];
    constexpr int P = PERa[L];
    constexpr int LDW = LDWa[L];
    if constexpr (L > 0) {
      const unsigned short* wl = wlds + WOFFa[L];
      const unsigned short* ob = outb[L - 1];
#pragma unroll
      for (int kt = 0; kt < NKT; kt++) {
        if (seg_type(L, kt * 32) != 1) continue;
        const int kloc = kt * 32 + quad * 8;     // ob segments start at k=0
        const unsigned short* p = ob + (size_t)(m0 + lm) * HSW + kloc;
        const short8 a0 = *(const short8*)p;
        const short8 a1 = *(const short8*)(p + 16 * HSW);
        const short8 bf0 = *(const short8*)(wl + (size_t)lm * LDW + kt * 32 + quad * 8);
        const short8 bf1 = *(const short8*)(wl + (size_t)(16 + lm) * LDW + kt * 32 + quad * 8);
        acc00 = mfma16(a0, bf0, acc00);
        acc01 = mfma16(a0, bf1, acc01);
        acc10 = mfma16(a1, bf0, acc10);
        acc11 = mfma16(a1, bf1, acc11);
      }
    }
    // gate exchange: lanes lm and lm^8 hold complementary gate columns
    f32x4 s00, s01, s10, s11;
#pragma unroll
    for (int r = 0; r < 4; r++) {
      s00[r] = __shfl_xor(acc00[r], 8);
      s01[r] = __shfl_xor(acc01[r], 8);
      s10[r] = __shfl_xor(acc10[r], 8);
      s11[r] = __shfl_xor(acc11[r], 8);
    }
    f32x4 G0, G1, G2, G3;
#pragma unroll
    for (int r = 0; r < 4; r++) {
      G0[r] = hi ? s10[r] : acc00[r];
      G1[r] = hi ? acc10[r] : s00[r];
      G2[r] = hi ? s11[r] : acc01[r];
      G3[r] = hi ? acc11[r] : s01[r];
    }
    // cell: this lane owns rows mrow..mrow+3, column j (global jg)
    float* cs = nullptr;
    if constexpr (L == 1) cs = bufC1 + ((size_t)(t % 3) * 8 + j) * ROWS + mrow;
    if constexpr (L == 2) cs = bufC2 + ((size_t)(t % 6) * 8 + j) * ROWS + mrow;
    float* cs3 = nullptr;
    if constexpr (L == 3) cs3 = c3l + ((size_t)(t % 12) * 8 + j) * C3STR + mrow;
    f32x4 dC = zero_f4();
    if constexpr (L == 1 || L == 2) { if (t >= DL) dC = *(const f32x4*)cs; }
    if constexpr (L == 3)           { if (t >= DL) dC = *(const f32x4*)cs3; }
    const f32x4 pcv = pc[L];
    f32x4 nC, wh;
#pragma unroll
    for (int q = 0; q < 4; q++) {
      const float fg = sigm(G0[q]);        // bias & +1.0 already in acc init
      const float cd = tanh_(G1[q]);
      const float og = sigm(G3[q]);
      float wc;
      if constexpr (L == 0) {
        wc = pcv[q];                       // dil=1: alpha*prevC+(1-alpha)*prevC
      } else {
        const float al = sigm(G2[q]);
        wc = (t >= DL) ? (al * pcv[q] + (1.0f - al) * dC[q]) : pcv[q];
      }
      const float nc = (t >= 1) ? (fg * wc + (1.0f - fg) * cd) : cd;
      nC[q] = nc;
      wh[q] = og * nc;
    }
    if constexpr (L == 1 || L == 2) *(f32x4*)cs = nC;
    if constexpr (L == 3)           *(f32x4*)cs3 = nC;
    pc[L] = nC;
    const int jg = g * 8 + j;
#pragma unroll
    for (int r = 0; r < 4; r++) {
      const unsigned short us = f2bf(wh[r]);
      const int row = mrow + r;
      if (g < 16) outb[L][(size_t)row * OSW + jg] = us;
      else bufH[L][((size_t)(t % P) * ROWS + row) * HSW + (jg - 128)] = us;
    }
  };

  // ---- epilogue: wave computes y for its private row r = m0 + g ----
  auto epilogue = [&](int tt) {
    const int r = m0 + g;
    const unsigned short* orow = outb[3] + (size_t)r * OSW;
    const int o = lane >> 3, s = lane & 7;
    const short8 v0 = *(const short8*)(orow + s * 16);
    const short8 v1 = *(const short8*)(orow + s * 16 + 8);
    float part = 0.f;
#pragma unroll
    for (int i = 0; i < 8; i++)
      part += bf2f((unsigned short)v0[i]) * woutl[o * WSTR + s * 16 + i];
#pragma unroll
    for (int i = 0; i < 8; i++)
      part += bf2f((unsigned short)v1[i]) * woutl[o * WSTR + s * 16 + 8 + i];
    part += __shfl_down(part, 4);
    part += __shfl_down(part, 2);
    part += __shfl_down(part, 1);
    if (s == 0)
      yout[((size_t)tt * BBATCH + (size_t)c * ROWS + r) * NO + o] = part + boutl[o];
  };

  // ---- main pipelined loop: POST(p) -> arrive(p) -> PRE(p+1) -> wait(p) ----
  pre(IC<0>{}, 0);
  for (int t = 0; t < TT; t++) {
    const unsigned pb = 4u * t;
    post(IC<0>{}, t); arrive(pb + 1); pre(IC<1>{}, t);
    if (t > 0) epilogue(t - 1);
    waitbar(pb + 1);
    post(IC<1>{}, t); arrive(pb + 2); pre(IC<2>{}, t); waitbar(pb + 2);
    post(IC<2>{}, t); arrive(pb + 3); pre(IC<3>{}, t); waitbar(pb + 3);
    post(IC<3>{}, t); arrive(pb + 4);
    if (t + 1 < TT) pre(IC<0>{}, t + 1);
    waitbar(pb + 4);
  }
  epilogue(TT - 1);
}

extern "C" void kernel_launch(void* const* d_in, const int* in_sizes, int n_in,
                              void* d_out, int out_size, void* d_ws, size_t ws_size,
                              hipStream_t stream) {
  const float* x    = (const float*)d_in[0];
  const float* W0   = (const float*)d_in[1];
  const float* b0   = (const float*)d_in[2];
  const float* W1   = (const float*)d_in[3];
  const float* b1   = (const float*)d_in[4];
  const float* W2   = (const float*)d_in[5];
  const float* b2   = (const float*)d_in[6];
  const float* W3   = (const float*)d_in[7];
  const float* b3   = (const float*)d_in[8];
  const float* Wout = (const float*)d_in[9];
  const float* bout = (const float*)d_in[10];
  float* out = (float*)d_out;
  char* ws = (char*)d_ws;

  if (ws_size < WS_NEED) {
    fprintf(stderr, "kernel_launch: ws_size %zu < needed %zu\n", ws_size, (size_t)WS_NEED);
    return;
  }

  // zero barrier flags + rank counters (ws is poisoned 0xAA before every launch)
  hipMemsetAsync(d_ws, 0, 8192, stream);

  hipError_t e = hipFuncSetAttribute((const void*)rnn_stack_kernel,
                                     hipFuncAttributeMaxDynamicSharedMemorySize,
                                     LDS_BYTES);
  if (e != hipSuccess) fprintf(stderr, "hipFuncSetAttribute: %d\n", (int)e);

  rnn_stack_kernel<<<dim3(256), dim3(256), LDS_BYTES, stream>>>(
      x, W0, b0, W1, b1, W2, b2, W3, b3, Wout, bout, out, ws);
  e = hipGetLastError();
  if (e != hipSuccess) fprintf(stderr, "launch error: %d\n", (int)e);
}